// Round 1
// baseline (791.339 us; speedup 1.0000x reference)
//
#include <hip/hip_runtime.h>
#include <math.h>

// Problem dims
namespace {
constexpr int NB = 512;
constexpr int NL = 50;
constexpr int NKN = 32;
constexpr int ND = 100;
constexpr int NV = 100000;
constexpr int NBL = NB * NL;          // 25600
constexpr int NJ = 900;               // P|Q|R concatenated width
}

// ---------------------------------------------------------------------------
// K0a: per-block partial column sums of E_tag  (for mean over V of logits)
// ---------------------------------------------------------------------------
__global__ __launch_bounds__(128) void ebar_partial(const float* __restrict__ E_tag,
                                                    float* __restrict__ partial)
{
    int blk = blockIdx.x;             // 512 blocks
    int tid = threadIdx.x;
    int v0 = blk * 196;
    int v1 = v0 + 196; if (v1 > NV) v1 = NV;
    if (tid < ND) {
        float acc = 0.f;
        for (int v = v0; v < v1; ++v) acc += E_tag[(size_t)v * ND + tid];
        partial[blk * ND + tid] = acc;
    }
}

__global__ __launch_bounds__(128) void ebar_final(const float* __restrict__ partial,
                                                  float* __restrict__ ebar)
{
    int tid = threadIdx.x;
    if (tid < ND) {
        float a = 0.f;
        for (int i = 0; i < 512; ++i) a += partial[i * ND + tid];
        ebar[tid] = a * (1.f / (float)NV);
    }
}

// ---------------------------------------------------------------------------
// K1: PQR = x @ [W_ih_top | W_ih_bot | W_hh]   (x = E_ggnn[seq], gathered)
//     M = 25600 rows, K = 100, N = 900.  Tile 32 rows x 128 cols, 256 thr,
//     micro-tile 2x8.
// ---------------------------------------------------------------------------
__global__ __launch_bounds__(256) void pqr_gemm(
    const int* __restrict__ seq, const float* __restrict__ E_ggnn,
    const float* __restrict__ W_ih, const float* __restrict__ W_hh,
    float* __restrict__ PQR)
{
    __shared__ float As[100][34];     // x^T tile (pad 34: keeps float2 8B-aligned)
    __shared__ float Bs[100][128];    // Wcat tile
    const int tid  = threadIdx.x;
    const int row0 = blockIdx.y * 32;
    const int j0   = blockIdx.x * 128;

    for (int idx = tid; idx < 32 * 100; idx += 256) {
        int rr = idx / 100, k = idx - rr * 100;
        int tok = seq[row0 + rr];
        As[k][rr] = E_ggnn[(size_t)tok * ND + k];
    }
    for (int idx = tid; idx < 100 * 128; idx += 256) {
        int k = idx >> 7, jj = idx & 127;
        int j = j0 + jj;
        float v = 0.f;
        if (j < 300)      v = W_ih[k * 300 + j];
        else if (j < 600) v = W_ih[(100 + k) * 300 + (j - 300)];
        else if (j < 900) v = W_hh[k * 300 + (j - 600)];
        Bs[k][jj] = v;
    }
    __syncthreads();

    const int tn = tid & 15, tm = tid >> 4;   // tn: 8 cols each, tm: 2 rows each
    float acc[2][8];
#pragma unroll
    for (int m = 0; m < 2; ++m)
#pragma unroll
        for (int n = 0; n < 8; ++n) acc[m][n] = 0.f;

    for (int k = 0; k < 100; ++k) {
        float2 av = *(const float2*)&As[k][2 * tm];
        float4 b0 = *(const float4*)&Bs[k][tn * 8];
        float4 b1 = *(const float4*)&Bs[k][tn * 8 + 4];
        float aa[2] = {av.x, av.y};
        float bb[8] = {b0.x, b0.y, b0.z, b0.w, b1.x, b1.y, b1.z, b1.w};
#pragma unroll
        for (int m = 0; m < 2; ++m)
#pragma unroll
            for (int n = 0; n < 8; ++n) acc[m][n] += aa[m] * bb[n];
    }

#pragma unroll
    for (int m = 0; m < 2; ++m) {
        int row = row0 + 2 * tm + m;
#pragma unroll
        for (int n = 0; n < 8; ++n) {
            int j = j0 + tn * 8 + n;
            if (j < NJ) PQR[(size_t)row * NJ + j] = acc[m][n];
        }
    }
}

// ---------------------------------------------------------------------------
// K2: GRU elementwise.  gi gets neighbor (shifted) P/Q contributions.
//     h0 = (1-z)*n + z*x
// ---------------------------------------------------------------------------
__global__ __launch_bounds__(256) void gru_kernel(
    const int* __restrict__ seq, const int* __restrict__ lens,
    const float* __restrict__ E_ggnn, const float* __restrict__ PQR,
    const float* __restrict__ b_ih, const float* __restrict__ b_hh,
    float* __restrict__ h0)
{
    int idx = blockIdx.x * 256 + threadIdx.x;
    if (idx >= NBL * ND) return;
    int r = idx / ND, d = idx - r * ND;
    int b = r / NL, l = r - b * NL;
    int lenb = lens[b];
    bool eo = (l < lenb - 1);
    bool ei = (l >= 1 && l <= lenb - 1);

    const float* Pr = PQR + (size_t)r * NJ;
    float ir = Pr[d]       + Pr[300 + d] + b_ih[d];
    float iz = Pr[100 + d] + Pr[400 + d] + b_ih[100 + d];
    float ig = Pr[200 + d] + Pr[500 + d] + b_ih[200 + d];
    if (eo) { ir += Pr[NJ + d];        iz += Pr[NJ + 100 + d];  ig += Pr[NJ + 200 + d]; }
    if (ei) { ir += Pr[-NJ + 300 + d]; iz += Pr[-NJ + 400 + d]; ig += Pr[-NJ + 500 + d]; }
    float hr = Pr[600 + d] + b_hh[d];
    float hz = Pr[700 + d] + b_hh[100 + d];
    float hg = Pr[800 + d] + b_hh[200 + d];

    float x  = E_ggnn[(size_t)seq[r] * ND + d];
    float rg = 1.f / (1.f + expf(-(ir + hr)));
    float zg = 1.f / (1.f + expf(-(iz + hz)));
    float ng = tanhf(ig + rg * hg);
    h0[idx] = (1.f - zg) * ng + zg * x;
}

// ---------------------------------------------------------------------------
// K45: per-batch fused: attention readout (with Wout folded), sess, mean_b,
//      global encoder, gate, sess2.  One block per b, 128 threads.
// ---------------------------------------------------------------------------
__global__ __launch_bounds__(128) void fuse_kernel(
    const int* __restrict__ seq, const int* __restrict__ lens,
    const int* __restrict__ nei, const float* __restrict__ wei,
    const float* __restrict__ s_vec, const float* __restrict__ E_tag,
    const float* __restrict__ E_glob,
    const float* __restrict__ Wout_w, const float* __restrict__ Wout_b,
    const float* __restrict__ W_w,
    const float* __restrict__ W3_w, const float* __restrict__ W3_b,
    const float* __restrict__ W1_w, const float* __restrict__ W1_b,
    const float* __restrict__ q1_w,
    const float* __restrict__ W2_w, const float* __restrict__ W2_b,
    const float* __restrict__ G1_w, const float* __restrict__ G1_b,
    const float* __restrict__ G2_w, const float* __restrict__ G2_b,
    const float* __restrict__ ebar, const float* __restrict__ h0,
    float* __restrict__ sess2)
{
    const int b = blockIdx.x, tid = threadIdx.x;
    __shared__ float t_emb[100], tw[100], twW[100], red[128];
    __shared__ float al[50], att[50];
    __shared__ float g0[100], cc[300], sess_s[100];
    __shared__ float sv[100], hnei[32][100], msg[100], xg[100], xg2[100];
    __shared__ float attg[32], score[32];
    __shared__ float scalars[4];      // 0: bd, 1: sm, 2: mean_b, 3: gate

    int lenb   = lens[b];
    int last_r = b * NL + (lenb - 1);
    int target = seq[last_r];

    if (tid < ND) {
        t_emb[tid] = E_tag[(size_t)target * ND + tid];
        sv[tid]    = s_vec[b * ND + tid];
    }
    __syncthreads();

    // tw = t_emb @ W_w
    if (tid < ND) {
        float a = 0.f;
        for (int k = 0; k < ND; ++k) a += t_emb[k] * W_w[k * ND + tid];
        tw[tid] = a;
    }
    __syncthreads();

    // twW[k] = Wout_w[k,:] . tw ; bd = Wout_b . tw
    if (tid < ND) {
        float a = 0.f;
        for (int d = 0; d < ND; ++d) a += Wout_w[tid * ND + d] * tw[d];
        twW[tid] = a;
    }
    red[tid] = (tid < ND) ? Wout_b[tid] * tw[tid] : 0.f;
    __syncthreads();
    for (int s = 64; s > 0; s >>= 1) { if (tid < s) red[tid] += red[tid + s]; __syncthreads(); }
    if (tid == 0) scalars[0] = red[0];
    __syncthreads();

    // attention logits over all 50 positions (softmax is unmasked in the ref)
    if (tid < NL) {
        const float* hr = h0 + (size_t)(b * NL + tid) * ND;
        float a = scalars[0];
        for (int k = 0; k < ND; ++k) a += hr[k] * twW[k];
        al[tid] = a;
    }
    __syncthreads();
    if (tid == 0) {
        float m = -1e30f;
        for (int l = 0; l < NL; ++l) m = fmaxf(m, al[l]);
        float s = 0.f;
        for (int l = 0; l < NL; ++l) { float e = expf(al[l] - m); att[l] = e; s += e; }
        float inv = 1.f / s, sm = 0.f;
        for (int l = 0; l < NL; ++l) { att[l] *= inv; if (l < lenb) sm += att[l]; }
        scalars[1] = sm;
    }
    __syncthreads();

    // g0 = sum_l att*mask*h0 ; then h_glb/h_last via Wout
    if (tid < ND) {
        float a = 0.f;
        for (int l = 0; l < lenb; ++l) a += att[l] * h0[(size_t)(b * NL + l) * ND + tid];
        g0[tid] = a;
    }
    __syncthreads();
    if (tid < ND) {
        float hg = 0.f, hl = 0.f;
        const float* hlast = h0 + (size_t)last_r * ND;
        for (int k = 0; k < ND; ++k) {
            float w = Wout_w[k * ND + tid];
            hg += g0[k] * w;
            hl += hlast[k] * w;
        }
        cc[tid]        = hg + scalars[1] * Wout_b[tid];
        cc[100 + tid]  = hl + Wout_b[tid];
        cc[200 + tid]  = t_emb[tid];
    }
    __syncthreads();

    // sess = tanh(cc @ W3 + b3) ; mean_b = sess . ebar
    if (tid < ND) {
        float a = W3_b[tid];
        for (int j = 0; j < 300; ++j) a += cc[j] * W3_w[j * ND + tid];
        sess_s[tid] = tanhf(a);
    }
    __syncthreads();
    red[tid] = (tid < ND) ? sess_s[tid] * ebar[tid] : 0.f;
    __syncthreads();
    for (int s = 64; s > 0; s >>= 1) { if (tid < s) red[tid] += red[tid + s]; __syncthreads(); }
    if (tid == 0) scalars[2] = red[0];
    __syncthreads();

    // ---- global encoder ----
    for (int idx = tid; idx < NKN * ND; idx += 128) {
        int k = idx / ND, d = idx - k * ND;
        hnei[k][d] = E_glob[(size_t)nei[b * NKN + k] * ND + d];
    }
    __syncthreads();

    for (int k = 0; k < NKN; ++k) {
        float p = 0.f;
        if (tid < ND) {
            float a = W1_b[tid];
            for (int j = 0; j < ND; ++j) a += hnei[k][j] * sv[j] * W1_w[j * ND + tid];
            a += wei[b * NKN + k] * W1_w[100 * ND + tid];
            p = tanhf(a) * q1_w[tid];
        }
        red[tid] = p;
        __syncthreads();
        for (int s = 64; s > 0; s >>= 1) { if (tid < s) red[tid] += red[tid + s]; __syncthreads(); }
        if (tid == 0) score[k] = red[0];
        __syncthreads();
    }
    if (tid == 0) {
        float m = -1e30f;
        for (int k = 0; k < NKN; ++k) m = fmaxf(m, score[k]);
        float s = 0.f;
        for (int k = 0; k < NKN; ++k) { float e = expf(score[k] - m); attg[k] = e; s += e; }
        float inv = 1.f / s;
        for (int k = 0; k < NKN; ++k) attg[k] *= inv;
    }
    __syncthreads();
    if (tid < ND) {
        float a = 0.f;
        for (int k = 0; k < NKN; ++k) a += attg[k] * hnei[k][tid];
        msg[tid] = a;
        xg[tid]  = E_glob[(size_t)target * ND + tid];
    }
    __syncthreads();
    // two relu layers
    if (tid < ND) {
        float a = W2_b[tid];
        for (int j = 0; j < ND; ++j) a += xg[j]  * W2_w[j * ND + tid];
        for (int j = 0; j < ND; ++j) a += msg[j] * W2_w[(100 + j) * ND + tid];
        xg2[tid] = fmaxf(a, 0.f);
    }
    __syncthreads();
    const float SCALE = (float)(1.0 - 49.0 / 50.0);
    if (tid < ND) {
        float a = W2_b[tid];
        for (int j = 0; j < ND; ++j) a += xg2[j] * W2_w[j * ND + tid];
        for (int j = 0; j < ND; ++j) a += msg[j] * W2_w[(100 + j) * ND + tid];
        xg[tid] = fmaxf(a, 0.f) * SCALE;
    }
    __syncthreads();

    // gate
    if (tid < ND) {
        float a = G1_b[tid] + scalars[2] * G1_w[tid];          // row 0 <- mean_b
        for (int j = 0; j < ND; ++j) a += xg[j] * G1_w[(1 + j) * ND + tid];
        red[tid] = tanhf(a) * G2_w[tid];
    } else red[tid] = 0.f;
    __syncthreads();
    for (int s = 64; s > 0; s >>= 1) { if (tid < s) red[tid] += red[tid + s]; __syncthreads(); }
    if (tid == 0) scalars[3] = 1.f / (1.f + expf(-(red[0] + G2_b[0])));
    __syncthreads();

    if (tid < ND) {
        float g = scalars[3];
        sess2[b * ND + tid] = g * xg[tid] + (1.f - g) * scalars[2];
    }
}

// ---------------------------------------------------------------------------
// K6: out = sess2 @ E_tag^T.   Tile 128 b x 64 v, 256 thr, micro 4x8.
// ---------------------------------------------------------------------------
__global__ __launch_bounds__(256) void out_gemm(
    const float* __restrict__ sess2, const float* __restrict__ E_tag,
    float* __restrict__ out)
{
    __shared__ float Ss[100][132];    // sess2^T tile (padded: spreads banks)
    __shared__ float Et[100][68];     // E_tag^T tile (padded)
    const int tid = threadIdx.x;
    const int v0  = blockIdx.x * 64;
    const int b0  = blockIdx.y * 128;

    for (int idx = tid; idx < 128 * 100; idx += 256) {
        int bb = idx / 100, k = idx - bb * 100;
        Ss[k][bb] = sess2[(b0 + bb) * ND + k];
    }
    for (int idx = tid; idx < 64 * 100; idx += 256) {
        int vv = idx / 100, k = idx - vv * 100;
        int v = v0 + vv;
        Et[k][vv] = (v < NV) ? E_tag[(size_t)v * ND + k] : 0.f;
    }
    __syncthreads();

    const int tv = tid & 7, tb = tid >> 3;   // tv: 8 v's, tb: 4 b's
    float acc[4][8];
#pragma unroll
    for (int m = 0; m < 4; ++m)
#pragma unroll
        for (int n = 0; n < 8; ++n) acc[m][n] = 0.f;

    for (int k = 0; k < 100; ++k) {
        float4 sb = *(const float4*)&Ss[k][tb * 4];
        float4 e0 = *(const float4*)&Et[k][tv * 8];
        float4 e1 = *(const float4*)&Et[k][tv * 8 + 4];
        float aa[4] = {sb.x, sb.y, sb.z, sb.w};
        float ee[8] = {e0.x, e0.y, e0.z, e0.w, e1.x, e1.y, e1.z, e1.w};
#pragma unroll
        for (int m = 0; m < 4; ++m)
#pragma unroll
            for (int n = 0; n < 8; ++n) acc[m][n] += aa[m] * ee[n];
    }

#pragma unroll
    for (int m = 0; m < 4; ++m) {
        int bb = b0 + tb * 4 + m;
        int v  = v0 + tv * 8;
        float* dst = out + (size_t)bb * NV + v;
        if (v + 7 < NV) {
            float4 s0 = make_float4(acc[m][0], acc[m][1], acc[m][2], acc[m][3]);
            float4 s1 = make_float4(acc[m][4], acc[m][5], acc[m][6], acc[m][7]);
            *(float4*)dst       = s0;
            *(float4*)(dst + 4) = s1;
        } else {
            for (int n = 0; n < 8; ++n) if (v + n < NV) dst[n] = acc[m][n];
        }
    }
}

// ---------------------------------------------------------------------------
extern "C" void kernel_launch(void* const* d_in, const int* in_sizes, int n_in,
                              void* d_out, int out_size, void* d_ws, size_t ws_size,
                              hipStream_t stream)
{
    const int*   seq    = (const int*)  d_in[0];
    const int*   lens   = (const int*)  d_in[1];
    const int*   nei    = (const int*)  d_in[2];
    const float* wei    = (const float*)d_in[3];
    const float* s_vec  = (const float*)d_in[4];
    const float* E_tag  = (const float*)d_in[5];
    const float* E_ggnn = (const float*)d_in[6];
    const float* E_glob = (const float*)d_in[7];
    const float* W_ih   = (const float*)d_in[8];
    const float* b_ih   = (const float*)d_in[9];
    const float* W_hh   = (const float*)d_in[10];
    const float* b_hh   = (const float*)d_in[11];
    const float* Wout_w = (const float*)d_in[12];
    const float* Wout_b = (const float*)d_in[13];
    const float* W_w    = (const float*)d_in[14];
    const float* W3_w   = (const float*)d_in[15];
    const float* W3_b   = (const float*)d_in[16];
    const float* W1_w   = (const float*)d_in[17];
    const float* W1_b   = (const float*)d_in[18];
    const float* q1_w   = (const float*)d_in[19];
    const float* W2_w   = (const float*)d_in[20];
    const float* W2_b   = (const float*)d_in[21];
    const float* G1_w   = (const float*)d_in[22];
    const float* G1_b   = (const float*)d_in[23];
    const float* G2_w   = (const float*)d_in[24];
    const float* G2_b   = (const float*)d_in[25];

    float* out = (float*)d_out;
    // PQR (23.04M floats) lives in d_out; it is fully consumed by gru_kernel
    // before out_gemm overwrites d_out.
    float* PQR = out;
    // ws: h0 (2.56M) + ebar partials (51.2K) + ebar (128) + sess2 (51.2K)
    float* ws      = (float*)d_ws;
    float* h0      = ws;
    float* partial = ws + 2560000;
    float* ebar    = ws + 2611200;
    float* sess2   = ws + 2611328;

    ebar_partial<<<512, 128, 0, stream>>>(E_tag, partial);
    ebar_final<<<1, 128, 0, stream>>>(partial, ebar);
    pqr_gemm<<<dim3(8, 800), 256, 0, stream>>>(seq, E_ggnn, W_ih, W_hh, PQR);
    gru_kernel<<<(NBL * ND + 255) / 256, 256, 0, stream>>>(seq, lens, E_ggnn, PQR,
                                                           b_ih, b_hh, h0);
    fuse_kernel<<<NB, 128, 0, stream>>>(seq, lens, nei, wei, s_vec, E_tag, E_glob,
                                        Wout_w, Wout_b, W_w, W3_w, W3_b,
                                        W1_w, W1_b, q1_w, W2_w, W2_b,
                                        G1_w, G1_b, G2_w, G2_b, ebar, h0, sess2);
    out_gemm<<<dim3((NV + 63) / 64, NB / 128), 256, 0, stream>>>(sess2, E_tag, out);
}

// Round 2
// 453.612 us; speedup vs baseline: 1.7445x; 1.7445x over previous
//
#include <hip/hip_runtime.h>
#include <math.h>

namespace {
constexpr int NB = 512;
constexpr int NL = 50;
constexpr int NKN = 32;
constexpr int ND = 100;
constexpr int NV = 100000;
constexpr int NBL = NB * NL;          // 25600
}

// ---------------------------------------------------------------------------
// K0a/K0b: column mean of E_tag
// ---------------------------------------------------------------------------
__global__ __launch_bounds__(128) void ebar_partial(const float* __restrict__ E_tag,
                                                    float* __restrict__ partial)
{
    int blk = blockIdx.x;             // 512 blocks
    int tid = threadIdx.x;
    int v0 = blk * 196;
    int v1 = v0 + 196; if (v1 > NV) v1 = NV;
    if (tid < ND) {
        float acc = 0.f;
        for (int v = v0; v < v1; ++v) acc += E_tag[(size_t)v * ND + tid];
        partial[blk * ND + tid] = acc;
    }
}

__global__ __launch_bounds__(128) void ebar_final(const float* __restrict__ partial,
                                                  float* __restrict__ ebar)
{
    int tid = threadIdx.x;
    if (tid < ND) {
        float a = 0.f;
        for (int i = 0; i < 512; ++i) a += partial[i * ND + tid];
        ebar[tid] = a * (1.f / (float)NV);
    }
}

// ---------------------------------------------------------------------------
// K1: gates GEMM.  G[r][0:300] = u@Wt + v@Wb ; G[r][300:600] = x@Whh
//     u = x[r]+eo*x[r+1], v = x[r]+ei*x[r-1] built from LDS-staged x rows.
//     Tile: 64 rows x 128 cols, 256 thr, micro 4x8.  W streamed from L2.
//     j-tiles overlap ({0,128,172}) so no tail guards: overlapped cols get
//     written twice with identical values (benign).
// ---------------------------------------------------------------------------
__global__ __launch_bounds__(256) void gates_gemm(
    const int* __restrict__ seq, const int* __restrict__ lens,
    const float* __restrict__ E_ggnn,
    const float* __restrict__ W_ih, const float* __restrict__ W_hh,
    float* __restrict__ G)
{
    __shared__ float xs[66][100];
    __shared__ float eo_s[66], ei_s[66];
    const int tid = threadIdx.x;
    const int r0  = blockIdx.y * 64;
    const int jt  = blockIdx.x;            // 0..5
    const bool is_gh = (jt >= 3);
    const int j3  = jt - (is_gh ? 3 : 0);
    const int jc0 = (j3 == 0) ? 0 : (j3 == 1 ? 128 : 172);

    for (int idx = tid; idx < 66 * 100; idx += 256) {
        int rr = idx / 100, kk = idx - rr * 100;
        int rg = r0 - 1 + rr;
        rg = rg < 0 ? 0 : (rg >= NBL ? NBL - 1 : rg);
        xs[rr][kk] = E_ggnn[(size_t)seq[rg] * ND + kk];
    }
    for (int rr = tid; rr < 66; rr += 256) {
        int rg = r0 - 1 + rr;
        int rc = rg < 0 ? 0 : (rg >= NBL ? NBL - 1 : rg);
        int b = rc / NL, l = rc - b * NL;
        int lenb = lens[b];
        eo_s[rr] = (l < lenb - 1) ? 1.f : 0.f;
        ei_s[rr] = (l >= 1 && l <= lenb - 1) ? 1.f : 0.f;
    }
    __syncthreads();

    const int tn = tid & 15, tb = tid >> 4;
    const int rbase = 1 + 4 * tb;
    const int jb = jc0 + 8 * tn;

    float acc[4][8];
#pragma unroll
    for (int m = 0; m < 4; ++m)
#pragma unroll
        for (int n = 0; n < 8; ++n) acc[m][n] = 0.f;

    if (!is_gh) {
        const float eo0 = eo_s[rbase],     eo1 = eo_s[rbase + 1],
                    eo2 = eo_s[rbase + 2], eo3 = eo_s[rbase + 3];
        const float ei0 = ei_s[rbase],     ei1 = ei_s[rbase + 1],
                    ei2 = ei_s[rbase + 2], ei3 = ei_s[rbase + 3];
#pragma unroll 2
        for (int kk = 0; kk < 100; ++kk) {      // u @ Wt
            float x0 = xs[rbase][kk],     x1 = xs[rbase + 1][kk],
                  x2 = xs[rbase + 2][kk], x3 = xs[rbase + 3][kk],
                  x4 = xs[rbase + 4][kk];
            float aa[4] = {x0 + eo0 * x1, x1 + eo1 * x2,
                           x2 + eo2 * x3, x3 + eo3 * x4};
            const float* Bp = W_ih + kk * 300 + jb;
            float4 b0 = *(const float4*)Bp, b1 = *(const float4*)(Bp + 4);
            float bb[8] = {b0.x, b0.y, b0.z, b0.w, b1.x, b1.y, b1.z, b1.w};
#pragma unroll
            for (int m = 0; m < 4; ++m)
#pragma unroll
                for (int n = 0; n < 8; ++n) acc[m][n] += aa[m] * bb[n];
        }
#pragma unroll 2
        for (int kk = 0; kk < 100; ++kk) {      // v @ Wb
            float xm = xs[rbase - 1][kk],
                  x0 = xs[rbase][kk],     x1 = xs[rbase + 1][kk],
                  x2 = xs[rbase + 2][kk], x3 = xs[rbase + 3][kk];
            float aa[4] = {x0 + ei0 * xm, x1 + ei1 * x0,
                           x2 + ei2 * x1, x3 + ei3 * x2};
            const float* Bp = W_ih + (100 + kk) * 300 + jb;
            float4 b0 = *(const float4*)Bp, b1 = *(const float4*)(Bp + 4);
            float bb[8] = {b0.x, b0.y, b0.z, b0.w, b1.x, b1.y, b1.z, b1.w};
#pragma unroll
            for (int m = 0; m < 4; ++m)
#pragma unroll
                for (int n = 0; n < 8; ++n) acc[m][n] += aa[m] * bb[n];
        }
    } else {
#pragma unroll 2
        for (int kk = 0; kk < 100; ++kk) {      // x @ Whh
            float aa[4] = {xs[rbase][kk], xs[rbase + 1][kk],
                           xs[rbase + 2][kk], xs[rbase + 3][kk]};
            const float* Bp = W_hh + kk * 300 + jb;
            float4 b0 = *(const float4*)Bp, b1 = *(const float4*)(Bp + 4);
            float bb[8] = {b0.x, b0.y, b0.z, b0.w, b1.x, b1.y, b1.z, b1.w};
#pragma unroll
            for (int m = 0; m < 4; ++m)
#pragma unroll
                for (int n = 0; n < 8; ++n) acc[m][n] += aa[m] * bb[n];
        }
    }

    const int cbase = (is_gh ? 300 : 0) + jb;
#pragma unroll
    for (int m = 0; m < 4; ++m) {
        float* dst = G + (size_t)(r0 + 4 * tb + m) * 600 + cbase;
        *(float4*)dst       = make_float4(acc[m][0], acc[m][1], acc[m][2], acc[m][3]);
        *(float4*)(dst + 4) = make_float4(acc[m][4], acc[m][5], acc[m][6], acc[m][7]);
    }
}

// ---------------------------------------------------------------------------
// K2: GRU elementwise (no neighbor reads; adjacency already folded into G)
// ---------------------------------------------------------------------------
__global__ __launch_bounds__(256) void gru2(
    const int* __restrict__ seq, const float* __restrict__ E_ggnn,
    const float* __restrict__ G,
    const float* __restrict__ b_ih, const float* __restrict__ b_hh,
    float* __restrict__ h0)
{
    int idx = blockIdx.x * 256 + threadIdx.x;
    if (idx >= NBL * ND) return;
    int r = idx / ND, d = idx - r * ND;
    const float* Gr = G + (size_t)r * 600;
    float ir = Gr[d]       + b_ih[d];
    float iz = Gr[100 + d] + b_ih[100 + d];
    float ig = Gr[200 + d] + b_ih[200 + d];
    float hr = Gr[300 + d] + b_hh[d];
    float hz = Gr[400 + d] + b_hh[100 + d];
    float hg = Gr[500 + d] + b_hh[200 + d];
    float x  = E_ggnn[(size_t)seq[r] * ND + d];
    float rg = 1.f / (1.f + expf(-(ir + hr)));
    float zg = 1.f / (1.f + expf(-(iz + hz)));
    float ng = tanhf(ig + rg * hg);
    h0[idx] = (1.f - zg) * ng + zg * x;
}

// ---------------------------------------------------------------------------
// K45: per-batch fused tail.  Writes sess2 TRANSPOSED [D][B] for out_gemm.
// ---------------------------------------------------------------------------
__global__ __launch_bounds__(128) void fuse_kernel(
    const int* __restrict__ seq, const int* __restrict__ lens,
    const int* __restrict__ nei, const float* __restrict__ wei,
    const float* __restrict__ s_vec, const float* __restrict__ E_tag,
    const float* __restrict__ E_glob,
    const float* __restrict__ Wout_w, const float* __restrict__ Wout_b,
    const float* __restrict__ W_w,
    const float* __restrict__ W3_w, const float* __restrict__ W3_b,
    const float* __restrict__ W1_w, const float* __restrict__ W1_b,
    const float* __restrict__ q1_w,
    const float* __restrict__ W2_w, const float* __restrict__ W2_b,
    const float* __restrict__ G1_w, const float* __restrict__ G1_b,
    const float* __restrict__ G2_w, const float* __restrict__ G2_b,
    const float* __restrict__ ebar, const float* __restrict__ h0,
    float* __restrict__ sess2T)
{
    const int b = blockIdx.x, tid = threadIdx.x;
    __shared__ float t_emb[100], tw[100], twW[100], red[128];
    __shared__ float al[50], att[50];
    __shared__ float g0[100], cc[300], sess_s[100];
    __shared__ float sv[100], hnei[32][100], msg[100], xg[100], xg2[100];
    __shared__ float attg[32], score[32];
    __shared__ float scalars[4];      // 0: bd, 1: sm, 2: mean_b, 3: gate

    int lenb   = lens[b];
    int last_r = b * NL + (lenb - 1);
    int target = seq[last_r];

    if (tid < ND) {
        t_emb[tid] = E_tag[(size_t)target * ND + tid];
        sv[tid]    = s_vec[b * ND + tid];
    }
    __syncthreads();

    if (tid < ND) {
        float a = 0.f;
        for (int k = 0; k < ND; ++k) a += t_emb[k] * W_w[k * ND + tid];
        tw[tid] = a;
    }
    __syncthreads();

    if (tid < ND) {
        float a = 0.f;
        for (int d = 0; d < ND; ++d) a += Wout_w[tid * ND + d] * tw[d];
        twW[tid] = a;
    }
    red[tid] = (tid < ND) ? Wout_b[tid] * tw[tid] : 0.f;
    __syncthreads();
    for (int s = 64; s > 0; s >>= 1) { if (tid < s) red[tid] += red[tid + s]; __syncthreads(); }
    if (tid == 0) scalars[0] = red[0];
    __syncthreads();

    if (tid < NL) {
        const float* hr = h0 + (size_t)(b * NL + tid) * ND;
        float a = scalars[0];
        for (int k = 0; k < ND; ++k) a += hr[k] * twW[k];
        al[tid] = a;
    }
    __syncthreads();
    if (tid == 0) {
        float m = -1e30f;
        for (int l = 0; l < NL; ++l) m = fmaxf(m, al[l]);
        float s = 0.f;
        for (int l = 0; l < NL; ++l) { float e = expf(al[l] - m); att[l] = e; s += e; }
        float inv = 1.f / s, sm = 0.f;
        for (int l = 0; l < NL; ++l) { att[l] *= inv; if (l < lenb) sm += att[l]; }
        scalars[1] = sm;
    }
    __syncthreads();

    if (tid < ND) {
        float a = 0.f;
        for (int l = 0; l < lenb; ++l) a += att[l] * h0[(size_t)(b * NL + l) * ND + tid];
        g0[tid] = a;
    }
    __syncthreads();
    if (tid < ND) {
        float hg = 0.f, hl = 0.f;
        const float* hlast = h0 + (size_t)last_r * ND;
        for (int k = 0; k < ND; ++k) {
            float w = Wout_w[k * ND + tid];
            hg += g0[k] * w;
            hl += hlast[k] * w;
        }
        cc[tid]        = hg + scalars[1] * Wout_b[tid];
        cc[100 + tid]  = hl + Wout_b[tid];
        cc[200 + tid]  = t_emb[tid];
    }
    __syncthreads();

    if (tid < ND) {
        float a = W3_b[tid];
        for (int j = 0; j < 300; ++j) a += cc[j] * W3_w[j * ND + tid];
        sess_s[tid] = tanhf(a);
    }
    __syncthreads();
    red[tid] = (tid < ND) ? sess_s[tid] * ebar[tid] : 0.f;
    __syncthreads();
    for (int s = 64; s > 0; s >>= 1) { if (tid < s) red[tid] += red[tid + s]; __syncthreads(); }
    if (tid == 0) scalars[2] = red[0];
    __syncthreads();

    // ---- global encoder ----
    for (int idx = tid; idx < NKN * ND; idx += 128) {
        int k = idx / ND, d = idx - k * ND;
        hnei[k][d] = E_glob[(size_t)nei[b * NKN + k] * ND + d];
    }
    __syncthreads();

    // neighbor scores: wave-parallel over k (2 waves x 16 k), shuffle reduce
    {
        const int wv = tid >> 6, lane = tid & 63;
        for (int k2 = 0; k2 < NKN / 2; ++k2) {
            int k = k2 * 2 + wv;
            float p = 0.f;
            if (lane < 50) {
                float wk = wei[b * NKN + k];
                float a0 = W1_b[lane]      + wk * W1_w[100 * ND + lane];
                float a1 = W1_b[lane + 50] + wk * W1_w[100 * ND + lane + 50];
                for (int j = 0; j < ND; ++j) {
                    float t = hnei[k][j] * sv[j];
                    a0 += t * W1_w[j * ND + lane];
                    a1 += t * W1_w[j * ND + lane + 50];
                }
                p = tanhf(a0) * q1_w[lane] + tanhf(a1) * q1_w[lane + 50];
            }
            for (int off = 32; off > 0; off >>= 1) p += __shfl_down(p, off);
            if (lane == 0) score[k] = p;
        }
    }
    __syncthreads();

    if (tid == 0) {
        float m = -1e30f;
        for (int k = 0; k < NKN; ++k) m = fmaxf(m, score[k]);
        float s = 0.f;
        for (int k = 0; k < NKN; ++k) { float e = expf(score[k] - m); attg[k] = e; s += e; }
        float inv = 1.f / s;
        for (int k = 0; k < NKN; ++k) attg[k] *= inv;
    }
    __syncthreads();
    if (tid < ND) {
        float a = 0.f;
        for (int k = 0; k < NKN; ++k) a += attg[k] * hnei[k][tid];
        msg[tid] = a;
        xg[tid]  = E_glob[(size_t)target * ND + tid];
    }
    __syncthreads();
    if (tid < ND) {
        float a = W2_b[tid];
        for (int j = 0; j < ND; ++j) a += xg[j]  * W2_w[j * ND + tid];
        for (int j = 0; j < ND; ++j) a += msg[j] * W2_w[(100 + j) * ND + tid];
        xg2[tid] = fmaxf(a, 0.f);
    }
    __syncthreads();
    const float SCALE = (float)(1.0 - 49.0 / 50.0);
    if (tid < ND) {
        float a = W2_b[tid];
        for (int j = 0; j < ND; ++j) a += xg2[j] * W2_w[j * ND + tid];
        for (int j = 0; j < ND; ++j) a += msg[j] * W2_w[(100 + j) * ND + tid];
        xg[tid] = fmaxf(a, 0.f) * SCALE;
    }
    __syncthreads();

    if (tid < ND) {
        float a = G1_b[tid] + scalars[2] * G1_w[tid];
        for (int j = 0; j < ND; ++j) a += xg[j] * G1_w[(1 + j) * ND + tid];
        red[tid] = tanhf(a) * G2_w[tid];
    } else red[tid] = 0.f;
    __syncthreads();
    for (int s = 64; s > 0; s >>= 1) { if (tid < s) red[tid] += red[tid + s]; __syncthreads(); }
    if (tid == 0) scalars[3] = 1.f / (1.f + expf(-(red[0] + G2_b[0])));
    __syncthreads();

    if (tid < ND) {
        float g = scalars[3];
        sess2T[tid * NB + b] = g * xg[tid] + (1.f - g) * scalars[2];
    }
}

// ---------------------------------------------------------------------------
// K6: out = sess2 @ E_tag^T.  Tile 128 b x 128 v, 256 thr, micro 8x8.
//     A (sess2T) streamed from L2; E_tag transposed into LDS conflict-free.
// ---------------------------------------------------------------------------
__global__ __launch_bounds__(256) void out_gemm(
    const float* __restrict__ sess2T, const float* __restrict__ E_tag,
    float* __restrict__ out)
{
    __shared__ float Et[100][132];
    const int tid = threadIdx.x;
    const int v0  = blockIdx.x * 128;
    const int b0  = blockIdx.y * 128;

    for (int idx = tid; idx < 128 * 25; idx += 256) {
        int vv = idx & 127, k4 = idx >> 7;
        int v = v0 + vv;
        float4 e = make_float4(0.f, 0.f, 0.f, 0.f);
        if (v < NV) e = *(const float4*)&E_tag[(size_t)v * ND + 4 * k4];
        Et[4 * k4 + 0][vv] = e.x;
        Et[4 * k4 + 1][vv] = e.y;
        Et[4 * k4 + 2][vv] = e.z;
        Et[4 * k4 + 3][vv] = e.w;
    }
    __syncthreads();

    const int tv = tid & 15, tb = tid >> 4;
    float acc[8][8];
#pragma unroll
    for (int m = 0; m < 8; ++m)
#pragma unroll
        for (int n = 0; n < 8; ++n) acc[m][n] = 0.f;

#pragma unroll 2
    for (int k = 0; k < 100; ++k) {
        const float* Ap = sess2T + k * NB + b0 + 8 * tb;
        float4 a0 = *(const float4*)Ap, a1 = *(const float4*)(Ap + 4);
        float4 e0 = *(const float4*)&Et[k][8 * tv];
        float4 e1 = *(const float4*)&Et[k][8 * tv + 4];
        float aa[8] = {a0.x, a0.y, a0.z, a0.w, a1.x, a1.y, a1.z, a1.w};
        float ee[8] = {e0.x, e0.y, e0.z, e0.w, e1.x, e1.y, e1.z, e1.w};
#pragma unroll
        for (int m = 0; m < 8; ++m)
#pragma unroll
            for (int n = 0; n < 8; ++n) acc[m][n] += aa[m] * ee[n];
    }

    const int v = v0 + 8 * tv;
#pragma unroll
    for (int m = 0; m < 8; ++m) {
        float* dst = out + (size_t)(b0 + 8 * tb + m) * NV + v;
        if (v + 7 < NV) {
            *(float4*)dst       = make_float4(acc[m][0], acc[m][1], acc[m][2], acc[m][3]);
            *(float4*)(dst + 4) = make_float4(acc[m][4], acc[m][5], acc[m][6], acc[m][7]);
        } else {
            for (int n = 0; n < 8; ++n) if (v + n < NV) dst[n] = acc[m][n];
        }
    }
}

// ---------------------------------------------------------------------------
extern "C" void kernel_launch(void* const* d_in, const int* in_sizes, int n_in,
                              void* d_out, int out_size, void* d_ws, size_t ws_size,
                              hipStream_t stream)
{
    const int*   seq    = (const int*)  d_in[0];
    const int*   lens   = (const int*)  d_in[1];
    const int*   nei    = (const int*)  d_in[2];
    const float* wei    = (const float*)d_in[3];
    const float* s_vec  = (const float*)d_in[4];
    const float* E_tag  = (const float*)d_in[5];
    const float* E_ggnn = (const float*)d_in[6];
    const float* E_glob = (const float*)d_in[7];
    const float* W_ih   = (const float*)d_in[8];
    const float* b_ih   = (const float*)d_in[9];
    const float* W_hh   = (const float*)d_in[10];
    const float* b_hh   = (const float*)d_in[11];
    const float* Wout_w = (const float*)d_in[12];
    const float* Wout_b = (const float*)d_in[13];
    const float* W_w    = (const float*)d_in[14];
    const float* W3_w   = (const float*)d_in[15];
    const float* W3_b   = (const float*)d_in[16];
    const float* W1_w   = (const float*)d_in[17];
    const float* W1_b   = (const float*)d_in[18];
    const float* q1_w   = (const float*)d_in[19];
    const float* W2_w   = (const float*)d_in[20];
    const float* W2_b   = (const float*)d_in[21];
    const float* G1_w   = (const float*)d_in[22];
    const float* G1_b   = (const float*)d_in[23];
    const float* G2_w   = (const float*)d_in[24];
    const float* G2_b   = (const float*)d_in[25];

    float* out = (float*)d_out;
    // G (25600x600 = 15.36M floats) staged in d_out, consumed by gru2 before
    // out_gemm overwrites d_out.
    float* Gm = out;
    float* ws      = (float*)d_ws;
    float* h0      = ws;                    // 2.56M
    float* partial = ws + 2560000;          // 51.2K
    float* ebar    = ws + 2611200;          // 128
    float* sess2T  = ws + 2611328;          // 51.2K  [D][B]

    ebar_partial<<<512, 128, 0, stream>>>(E_tag, partial);
    ebar_final<<<1, 128, 0, stream>>>(partial, ebar);
    gates_gemm<<<dim3(6, NBL / 64), 256, 0, stream>>>(seq, lens, E_ggnn, W_ih, W_hh, Gm);
    gru2<<<(NBL * ND + 255) / 256, 256, 0, stream>>>(seq, E_ggnn, Gm, b_ih, b_hh, h0);
    fuse_kernel<<<NB, 128, 0, stream>>>(seq, lens, nei, wei, s_vec, E_tag, E_glob,
                                        Wout_w, Wout_b, W_w, W3_w, W3_b,
                                        W1_w, W1_b, q1_w, W2_w, W2_b,
                                        G1_w, G1_b, G2_w, G2_b, ebar, h0, sess2T);
    out_gemm<<<dim3((NV + 127) / 128, NB / 128), 256, 0, stream>>>(sess2T, E_tag, out);
}

// Round 3
// 379.473 us; speedup vs baseline: 2.0854x; 1.1954x over previous
//
#include <hip/hip_runtime.h>
#include <math.h>

namespace {
constexpr int NB = 512;
constexpr int NL = 50;
constexpr int NKN = 32;
constexpr int ND = 100;
constexpr int NV = 100000;
constexpr int NBL = NB * NL;          // 25600
}

typedef __attribute__((ext_vector_type(8))) short bf16x8;
typedef __attribute__((ext_vector_type(4))) short short4v;
typedef __attribute__((ext_vector_type(8))) short short8v;
typedef __attribute__((ext_vector_type(4))) float f32x4;

__device__ inline unsigned short f2bf(float x) {
    unsigned u = __float_as_uint(x);
    unsigned r = (u + 0x7fffu + ((u >> 16) & 1u)) >> 16;
    return (unsigned short)r;
}
__device__ inline float bf2f(unsigned short h) {
    return __uint_as_float(((unsigned)h) << 16);
}

// ---------------------------------------------------------------------------
// K0a/K0b: column mean of E_tag
// ---------------------------------------------------------------------------
__global__ __launch_bounds__(128) void ebar_partial(const float* __restrict__ E_tag,
                                                    float* __restrict__ partial)
{
    int blk = blockIdx.x;             // 512 blocks
    int tid = threadIdx.x;
    int v0 = blk * 196;
    int v1 = v0 + 196; if (v1 > NV) v1 = NV;
    if (tid < ND) {
        float acc = 0.f;
        for (int v = v0; v < v1; ++v) acc += E_tag[(size_t)v * ND + tid];
        partial[blk * ND + tid] = acc;
    }
}

__global__ __launch_bounds__(128) void ebar_final(const float* __restrict__ partial,
                                                  float* __restrict__ ebar)
{
    int tid = threadIdx.x;
    if (tid < ND) {
        float a = 0.f;
        for (int i = 0; i < 512; ++i) a += partial[i * ND + tid];
        ebar[tid] = a * (1.f / (float)NV);
    }
}

// ---------------------------------------------------------------------------
// K1: gates GEMM (fp32 VALU).  G[r][0:300] = u@Wt + v@Wb ; G[r][300:600]=x@Whh
// ---------------------------------------------------------------------------
__global__ __launch_bounds__(256) void gates_gemm(
    const int* __restrict__ seq, const int* __restrict__ lens,
    const float* __restrict__ E_ggnn,
    const float* __restrict__ W_ih, const float* __restrict__ W_hh,
    float* __restrict__ G)
{
    __shared__ float xs[66][100];
    __shared__ float eo_s[66], ei_s[66];
    const int tid = threadIdx.x;
    const int r0  = blockIdx.y * 64;
    const int jt  = blockIdx.x;            // 0..5
    const bool is_gh = (jt >= 3);
    const int j3  = jt - (is_gh ? 3 : 0);
    const int jc0 = (j3 == 0) ? 0 : (j3 == 1 ? 128 : 172);

    for (int idx = tid; idx < 66 * 100; idx += 256) {
        int rr = idx / 100, kk = idx - rr * 100;
        int rg = r0 - 1 + rr;
        rg = rg < 0 ? 0 : (rg >= NBL ? NBL - 1 : rg);
        xs[rr][kk] = E_ggnn[(size_t)seq[rg] * ND + kk];
    }
    for (int rr = tid; rr < 66; rr += 256) {
        int rg = r0 - 1 + rr;
        int rc = rg < 0 ? 0 : (rg >= NBL ? NBL - 1 : rg);
        int b = rc / NL, l = rc - b * NL;
        int lenb = lens[b];
        eo_s[rr] = (l < lenb - 1) ? 1.f : 0.f;
        ei_s[rr] = (l >= 1 && l <= lenb - 1) ? 1.f : 0.f;
    }
    __syncthreads();

    const int tn = tid & 15, tb = tid >> 4;
    const int rbase = 1 + 4 * tb;
    const int jb = jc0 + 8 * tn;

    float acc[4][8];
#pragma unroll
    for (int m = 0; m < 4; ++m)
#pragma unroll
        for (int n = 0; n < 8; ++n) acc[m][n] = 0.f;

    if (!is_gh) {
        const float eo0 = eo_s[rbase],     eo1 = eo_s[rbase + 1],
                    eo2 = eo_s[rbase + 2], eo3 = eo_s[rbase + 3];
        const float ei0 = ei_s[rbase],     ei1 = ei_s[rbase + 1],
                    ei2 = ei_s[rbase + 2], ei3 = ei_s[rbase + 3];
#pragma unroll 2
        for (int kk = 0; kk < 100; ++kk) {      // u @ Wt
            float x0 = xs[rbase][kk],     x1 = xs[rbase + 1][kk],
                  x2 = xs[rbase + 2][kk], x3 = xs[rbase + 3][kk],
                  x4 = xs[rbase + 4][kk];
            float aa[4] = {x0 + eo0 * x1, x1 + eo1 * x2,
                           x2 + eo2 * x3, x3 + eo3 * x4};
            const float* Bp = W_ih + kk * 300 + jb;
            float4 b0 = *(const float4*)Bp, b1 = *(const float4*)(Bp + 4);
            float bb[8] = {b0.x, b0.y, b0.z, b0.w, b1.x, b1.y, b1.z, b1.w};
#pragma unroll
            for (int m = 0; m < 4; ++m)
#pragma unroll
                for (int n = 0; n < 8; ++n) acc[m][n] += aa[m] * bb[n];
        }
#pragma unroll 2
        for (int kk = 0; kk < 100; ++kk) {      // v @ Wb
            float xm = xs[rbase - 1][kk],
                  x0 = xs[rbase][kk],     x1 = xs[rbase + 1][kk],
                  x2 = xs[rbase + 2][kk], x3 = xs[rbase + 3][kk];
            float aa[4] = {x0 + ei0 * xm, x1 + ei1 * x0,
                           x2 + ei2 * x1, x3 + ei3 * x2};
            const float* Bp = W_ih + (100 + kk) * 300 + jb;
            float4 b0 = *(const float4*)Bp, b1 = *(const float4*)(Bp + 4);
            float bb[8] = {b0.x, b0.y, b0.z, b0.w, b1.x, b1.y, b1.z, b1.w};
#pragma unroll
            for (int m = 0; m < 4; ++m)
#pragma unroll
                for (int n = 0; n < 8; ++n) acc[m][n] += aa[m] * bb[n];
        }
    } else {
#pragma unroll 2
        for (int kk = 0; kk < 100; ++kk) {      // x @ Whh
            float aa[4] = {xs[rbase][kk], xs[rbase + 1][kk],
                           xs[rbase + 2][kk], xs[rbase + 3][kk]};
            const float* Bp = W_hh + kk * 300 + jb;
            float4 b0 = *(const float4*)Bp, b1 = *(const float4*)(Bp + 4);
            float bb[8] = {b0.x, b0.y, b0.z, b0.w, b1.x, b1.y, b1.z, b1.w};
#pragma unroll
            for (int m = 0; m < 4; ++m)
#pragma unroll
                for (int n = 0; n < 8; ++n) acc[m][n] += aa[m] * bb[n];
        }
    }

    const int cbase = (is_gh ? 300 : 0) + jb;
#pragma unroll
    for (int m = 0; m < 4; ++m) {
        float* dst = G + (size_t)(r0 + 4 * tb + m) * 600 + cbase;
        *(float4*)dst       = make_float4(acc[m][0], acc[m][1], acc[m][2], acc[m][3]);
        *(float4*)(dst + 4) = make_float4(acc[m][4], acc[m][5], acc[m][6], acc[m][7]);
    }
}

// ---------------------------------------------------------------------------
// K2: GRU elementwise
// ---------------------------------------------------------------------------
__global__ __launch_bounds__(256) void gru2(
    const int* __restrict__ seq, const float* __restrict__ E_ggnn,
    const float* __restrict__ G,
    const float* __restrict__ b_ih, const float* __restrict__ b_hh,
    float* __restrict__ h0)
{
    int idx = blockIdx.x * 256 + threadIdx.x;
    if (idx >= NBL * ND) return;
    int r = idx / ND, d = idx - r * ND;
    const float* Gr = G + (size_t)r * 600;
    float ir = Gr[d]       + b_ih[d];
    float iz = Gr[100 + d] + b_ih[100 + d];
    float ig = Gr[200 + d] + b_ih[200 + d];
    float hr = Gr[300 + d] + b_hh[d];
    float hz = Gr[400 + d] + b_hh[100 + d];
    float hg = Gr[500 + d] + b_hh[200 + d];
    float x  = E_ggnn[(size_t)seq[r] * ND + d];
    float rg = 1.f / (1.f + expf(-(ir + hr)));
    float zg = 1.f / (1.f + expf(-(iz + hz)));
    float ng = tanhf(ig + rg * hg);
    h0[idx] = (1.f - zg) * ng + zg * x;
}

// ---------------------------------------------------------------------------
// K45: per-batch fused tail.  Writes sess2 split hi/lo bf16 in MFMA fragment
//      layout A[kgrp 0..15][512 rows][8]  (k = kgrp*8+j, zero-padded k>=100).
// ---------------------------------------------------------------------------
__global__ __launch_bounds__(128) void fuse_kernel(
    const int* __restrict__ seq, const int* __restrict__ lens,
    const int* __restrict__ nei, const float* __restrict__ wei,
    const float* __restrict__ s_vec, const float* __restrict__ E_tag,
    const float* __restrict__ E_glob,
    const float* __restrict__ Wout_w, const float* __restrict__ Wout_b,
    const float* __restrict__ W_w,
    const float* __restrict__ W3_w, const float* __restrict__ W3_b,
    const float* __restrict__ W1_w, const float* __restrict__ W1_b,
    const float* __restrict__ q1_w,
    const float* __restrict__ W2_w, const float* __restrict__ W2_b,
    const float* __restrict__ G1_w, const float* __restrict__ G1_b,
    const float* __restrict__ G2_w, const float* __restrict__ G2_b,
    const float* __restrict__ ebar, const float* __restrict__ h0,
    unsigned short* __restrict__ A_hi, unsigned short* __restrict__ A_lo)
{
    const int b = blockIdx.x, tid = threadIdx.x;
    __shared__ float t_emb[100], tw[100], twW[100], red[128];
    __shared__ float al[50], att[50];
    __shared__ float g0[100], cc[300], sess_s[100];
    __shared__ float sv[100], hnei[32][100], msg[100], xg[100], xg2[100];
    __shared__ float attg[32], score[32];
    __shared__ float scalars[4];      // 0: bd, 1: sm, 2: mean_b, 3: gate

    int lenb   = lens[b];
    int last_r = b * NL + (lenb - 1);
    int target = seq[last_r];

    if (tid < ND) {
        t_emb[tid] = E_tag[(size_t)target * ND + tid];
        sv[tid]    = s_vec[b * ND + tid];
    }
    __syncthreads();

    if (tid < ND) {
        float a = 0.f;
        for (int k = 0; k < ND; ++k) a += t_emb[k] * W_w[k * ND + tid];
        tw[tid] = a;
    }
    __syncthreads();

    if (tid < ND) {
        float a = 0.f;
        for (int d = 0; d < ND; ++d) a += Wout_w[tid * ND + d] * tw[d];
        twW[tid] = a;
    }
    red[tid] = (tid < ND) ? Wout_b[tid] * tw[tid] : 0.f;
    __syncthreads();
    for (int s = 64; s > 0; s >>= 1) { if (tid < s) red[tid] += red[tid + s]; __syncthreads(); }
    if (tid == 0) scalars[0] = red[0];
    __syncthreads();

    if (tid < NL) {
        const float* hr = h0 + (size_t)(b * NL + tid) * ND;
        float a = scalars[0];
        for (int k = 0; k < ND; ++k) a += hr[k] * twW[k];
        al[tid] = a;
    }
    __syncthreads();
    if (tid == 0) {
        float m = -1e30f;
        for (int l = 0; l < NL; ++l) m = fmaxf(m, al[l]);
        float s = 0.f;
        for (int l = 0; l < NL; ++l) { float e = expf(al[l] - m); att[l] = e; s += e; }
        float inv = 1.f / s, sm = 0.f;
        for (int l = 0; l < NL; ++l) { att[l] *= inv; if (l < lenb) sm += att[l]; }
        scalars[1] = sm;
    }
    __syncthreads();

    if (tid < ND) {
        float a = 0.f;
        for (int l = 0; l < lenb; ++l) a += att[l] * h0[(size_t)(b * NL + l) * ND + tid];
        g0[tid] = a;
    }
    __syncthreads();
    if (tid < ND) {
        float hg = 0.f, hl = 0.f;
        const float* hlast = h0 + (size_t)last_r * ND;
        for (int k = 0; k < ND; ++k) {
            float w = Wout_w[k * ND + tid];
            hg += g0[k] * w;
            hl += hlast[k] * w;
        }
        cc[tid]        = hg + scalars[1] * Wout_b[tid];
        cc[100 + tid]  = hl + Wout_b[tid];
        cc[200 + tid]  = t_emb[tid];
    }
    __syncthreads();

    if (tid < ND) {
        float a = W3_b[tid];
        for (int j = 0; j < 300; ++j) a += cc[j] * W3_w[j * ND + tid];
        sess_s[tid] = tanhf(a);
    }
    __syncthreads();
    red[tid] = (tid < ND) ? sess_s[tid] * ebar[tid] : 0.f;
    __syncthreads();
    for (int s = 64; s > 0; s >>= 1) { if (tid < s) red[tid] += red[tid + s]; __syncthreads(); }
    if (tid == 0) scalars[2] = red[0];
    __syncthreads();

    // ---- global encoder ----
    for (int idx = tid; idx < NKN * ND; idx += 128) {
        int k = idx / ND, d = idx - k * ND;
        hnei[k][d] = E_glob[(size_t)nei[b * NKN + k] * ND + d];
    }
    __syncthreads();

    {
        const int wv = tid >> 6, lane = tid & 63;
        for (int k2 = 0; k2 < NKN / 2; ++k2) {
            int k = k2 * 2 + wv;
            float p = 0.f;
            if (lane < 50) {
                float wk = wei[b * NKN + k];
                float a0 = W1_b[lane]      + wk * W1_w[100 * ND + lane];
                float a1 = W1_b[lane + 50] + wk * W1_w[100 * ND + lane + 50];
                for (int j = 0; j < ND; ++j) {
                    float t = hnei[k][j] * sv[j];
                    a0 += t * W1_w[j * ND + lane];
                    a1 += t * W1_w[j * ND + lane + 50];
                }
                p = tanhf(a0) * q1_w[lane] + tanhf(a1) * q1_w[lane + 50];
            }
            for (int off = 32; off > 0; off >>= 1) p += __shfl_down(p, off);
            if (lane == 0) score[k] = p;
        }
    }
    __syncthreads();

    if (tid == 0) {
        float m = -1e30f;
        for (int k = 0; k < NKN; ++k) m = fmaxf(m, score[k]);
        float s = 0.f;
        for (int k = 0; k < NKN; ++k) { float e = expf(score[k] - m); attg[k] = e; s += e; }
        float inv = 1.f / s;
        for (int k = 0; k < NKN; ++k) attg[k] *= inv;
    }
    __syncthreads();
    if (tid < ND) {
        float a = 0.f;
        for (int k = 0; k < NKN; ++k) a += attg[k] * hnei[k][tid];
        msg[tid] = a;
        xg[tid]  = E_glob[(size_t)target * ND + tid];
    }
    __syncthreads();
    if (tid < ND) {
        float a = W2_b[tid];
        for (int j = 0; j < ND; ++j) a += xg[j]  * W2_w[j * ND + tid];
        for (int j = 0; j < ND; ++j) a += msg[j] * W2_w[(100 + j) * ND + tid];
        xg2[tid] = fmaxf(a, 0.f);
    }
    __syncthreads();
    const float SCALE = (float)(1.0 - 49.0 / 50.0);
    if (tid < ND) {
        float a = W2_b[tid];
        for (int j = 0; j < ND; ++j) a += xg2[j] * W2_w[j * ND + tid];
        for (int j = 0; j < ND; ++j) a += msg[j] * W2_w[(100 + j) * ND + tid];
        xg[tid] = fmaxf(a, 0.f) * SCALE;
    }
    __syncthreads();

    if (tid < ND) {
        float a = G1_b[tid] + scalars[2] * G1_w[tid];
        for (int j = 0; j < ND; ++j) a += xg[j] * G1_w[(1 + j) * ND + tid];
        red[tid] = tanhf(a) * G2_w[tid];
    } else red[tid] = 0.f;
    __syncthreads();
    for (int s = 64; s > 0; s >>= 1) { if (tid < s) red[tid] += red[tid + s]; __syncthreads(); }
    if (tid == 0) scalars[3] = 1.f / (1.f + expf(-(red[0] + G2_b[0])));
    __syncthreads();

    // sess2 -> hi/lo bf16 fragment layout (k = tid; tid>=100 pads zero)
    {
        float val = 0.f;
        if (tid < ND) {
            float g = scalars[3];
            val = g * xg[tid] + (1.f - g) * scalars[2];
        }
        int kgrp = tid >> 3, j = tid & 7;
        unsigned short h = f2bf(val);
        A_hi[kgrp * 4096 + b * 8 + j] = h;
        A_lo[kgrp * 4096 + b * 8 + j] = f2bf(val - bf2f(h));
    }
}

// ---------------------------------------------------------------------------
// K6: out = sess2 @ E_tag^T via MFMA 16x16x32 bf16, hi/lo split (3 products).
//     BM=128 x BN=128, 4 waves (64x64 each), Kp=128 (k>=100 zero).
//     B tile (E_tag cols) converted fp32->hi/lo bf16 into LDS frag layout
//     [kgrp][col][8] with +16-short kgrp-stride pad. A frags read from global.
// ---------------------------------------------------------------------------
__global__ __launch_bounds__(256) void out_gemm_mfma(
    const unsigned short* __restrict__ A_hi, const unsigned short* __restrict__ A_lo,
    const float* __restrict__ E_tag, float* __restrict__ out)
{
    __shared__ __align__(16) unsigned short Bhi[16 * 1040];  // 1040 = 128*8 + 16 pad
    __shared__ __align__(16) unsigned short Blo[16 * 1040];

    const int tid = threadIdx.x;
    const int v0  = blockIdx.x * 128;
    const int b0  = blockIdx.y * 128;

    // zero pad region (kgrp 12..15) so garbage never reaches MFMA
    {
        short8v z = {0, 0, 0, 0, 0, 0, 0, 0};
        for (int idx = tid; idx < 2 * 520; idx += 256) {
            int a = idx >= 520;
            int o = idx - a * 520;
            short8v* base = (short8v*)((a ? Blo : Bhi) + 12 * 1040);
            base[o] = z;
        }
    }
    __syncthreads();

    // fill k<100: each idx handles one float4 (4 k's) of one E_tag row
    for (int idx = tid; idx < 128 * 25; idx += 256) {
        int row = idx / 25, qq = idx - row * 25;
        int v = v0 + row;
        float4 e = make_float4(0.f, 0.f, 0.f, 0.f);
        if (v < NV) e = *(const float4*)(E_tag + (size_t)v * ND + 4 * qq);
        int kgrp = qq >> 1, jo = (qq & 1) * 4;
        float ev[4] = {e.x, e.y, e.z, e.w};
        short4v h, l;
#pragma unroll
        for (int t = 0; t < 4; ++t) {
            unsigned short hh = f2bf(ev[t]);
            h[t] = (short)hh;
            l[t] = (short)f2bf(ev[t] - bf2f(hh));
        }
        int off = kgrp * 1040 + row * 8 + jo;
        *(short4v*)(Bhi + off) = h;
        *(short4v*)(Blo + off) = l;
    }
    __syncthreads();

    const int lane = tid & 63;
    const int wv = tid >> 6;
    const int wm = wv >> 1, wn = wv & 1;      // wave tile: rows wm*64, cols wn*64
    const int q = lane >> 4, c = lane & 15;

    f32x4 acc[4][4];
#pragma unroll
    for (int fm = 0; fm < 4; ++fm)
#pragma unroll
        for (int fn = 0; fn < 4; ++fn) acc[fm][fn] = (f32x4)0.f;

    const bf16x8* Ah = (const bf16x8*)A_hi;
    const bf16x8* Al = (const bf16x8*)A_lo;

#pragma unroll
    for (int s = 0; s < 4; ++s) {
        const int kg = 4 * s + q;
        bf16x8 ah[4], al[4], bh[4], bl[4];
#pragma unroll
        for (int fm = 0; fm < 4; ++fm) {
            int row = b0 + wm * 64 + fm * 16 + c;
            ah[fm] = Ah[kg * 512 + row];
            al[fm] = Al[kg * 512 + row];
        }
#pragma unroll
        for (int fn = 0; fn < 4; ++fn) {
            int vloc = wn * 64 + fn * 16 + c;
            bh[fn] = *(const bf16x8*)(Bhi + kg * 1040 + vloc * 8);
            bl[fn] = *(const bf16x8*)(Blo + kg * 1040 + vloc * 8);
        }
#pragma unroll
        for (int fm = 0; fm < 4; ++fm)
#pragma unroll
            for (int fn = 0; fn < 4; ++fn) {
                acc[fm][fn] = __builtin_amdgcn_mfma_f32_16x16x32_bf16(
                    ah[fm], bh[fn], acc[fm][fn], 0, 0, 0);
                acc[fm][fn] = __builtin_amdgcn_mfma_f32_16x16x32_bf16(
                    ah[fm], bl[fn], acc[fm][fn], 0, 0, 0);
                acc[fm][fn] = __builtin_amdgcn_mfma_f32_16x16x32_bf16(
                    al[fm], bh[fn], acc[fm][fn], 0, 0, 0);
            }
    }

    // store: D row = (lane>>4)*4 + reg (batch), col = lane&15 (v)
#pragma unroll
    for (int fm = 0; fm < 4; ++fm) {
        int row_base = b0 + wm * 64 + fm * 16 + q * 4;
#pragma unroll
        for (int fn = 0; fn < 4; ++fn) {
            int col = v0 + wn * 64 + fn * 16 + c;
            if (col < NV) {
#pragma unroll
                for (int r = 0; r < 4; ++r)
                    out[(size_t)(row_base + r) * NV + col] = acc[fm][fn][r];
            }
        }
    }
}

// ---------------------------------------------------------------------------
extern "C" void kernel_launch(void* const* d_in, const int* in_sizes, int n_in,
                              void* d_out, int out_size, void* d_ws, size_t ws_size,
                              hipStream_t stream)
{
    const int*   seq    = (const int*)  d_in[0];
    const int*   lens   = (const int*)  d_in[1];
    const int*   nei    = (const int*)  d_in[2];
    const float* wei    = (const float*)d_in[3];
    const float* s_vec  = (const float*)d_in[4];
    const float* E_tag  = (const float*)d_in[5];
    const float* E_ggnn = (const float*)d_in[6];
    const float* E_glob = (const float*)d_in[7];
    const float* W_ih   = (const float*)d_in[8];
    const float* b_ih   = (const float*)d_in[9];
    const float* W_hh   = (const float*)d_in[10];
    const float* b_hh   = (const float*)d_in[11];
    const float* Wout_w = (const float*)d_in[12];
    const float* Wout_b = (const float*)d_in[13];
    const float* W_w    = (const float*)d_in[14];
    const float* W3_w   = (const float*)d_in[15];
    const float* W3_b   = (const float*)d_in[16];
    const float* W1_w   = (const float*)d_in[17];
    const float* W1_b   = (const float*)d_in[18];
    const float* q1_w   = (const float*)d_in[19];
    const float* W2_w   = (const float*)d_in[20];
    const float* W2_b   = (const float*)d_in[21];
    const float* G1_w   = (const float*)d_in[22];
    const float* G1_b   = (const float*)d_in[23];
    const float* G2_w   = (const float*)d_in[24];
    const float* G2_b   = (const float*)d_in[25];

    float* out = (float*)d_out;
    // G (25600x600) staged in d_out, consumed by gru2 before out_gemm overwrites.
    float* Gm = out;
    float* ws      = (float*)d_ws;
    float* h0      = ws;                            // 2.56M floats
    float* partial = ws + 2560000;                  // 51.2K
    float* ebar    = ws + 2611200;                  // 128
    unsigned short* A_hi = (unsigned short*)(ws + 2611328);  // 65536 bf16
    unsigned short* A_lo = (unsigned short*)(ws + 2644096);  // 65536 bf16

    ebar_partial<<<512, 128, 0, stream>>>(E_tag, partial);
    ebar_final<<<1, 128, 0, stream>>>(partial, ebar);
    gates_gemm<<<dim3(6, NBL / 64), 256, 0, stream>>>(seq, lens, E_ggnn, W_ih, W_hh, Gm);
    gru2<<<(NBL * ND + 255) / 256, 256, 0, stream>>>(seq, E_ggnn, Gm, b_ih, b_hh, h0);
    fuse_kernel<<<NB, 128, 0, stream>>>(seq, lens, nei, wei, s_vec, E_tag, E_glob,
                                        Wout_w, Wout_b, W_w, W3_w, W3_b,
                                        W1_w, W1_b, q1_w, W2_w, W2_b,
                                        G1_w, G1_b, G2_w, G2_b, ebar, h0, A_hi, A_lo);
    out_gemm_mfma<<<dim3((NV + 127) / 128, NB / 128), 256, 0, stream>>>(A_hi, A_lo,
                                                                        E_tag, out);
}

// Round 4
// 281.600 us; speedup vs baseline: 2.8102x; 1.3476x over previous
//
#include <hip/hip_runtime.h>
#include <math.h>

namespace {
constexpr int NB = 512;
constexpr int NL = 50;
constexpr int NKN = 32;
constexpr int ND = 100;
constexpr int NV = 100000;
constexpr int NBL = NB * NL;          // 25600
}

typedef __attribute__((ext_vector_type(8))) short bf16x8;
typedef __attribute__((ext_vector_type(4))) short short4v;
typedef __attribute__((ext_vector_type(8))) short short8v;
typedef __attribute__((ext_vector_type(4))) float f32x4;

__device__ inline unsigned short f2bf(float x) {
    unsigned u = __float_as_uint(x);
    unsigned r = (u + 0x7fffu + ((u >> 16) & 1u)) >> 16;
    return (unsigned short)r;
}
__device__ inline float bf2f(unsigned short h) {
    return __uint_as_float(((unsigned)h) << 16);
}

// ---------------------------------------------------------------------------
// K0a/K0b: column mean of E_tag
// ---------------------------------------------------------------------------
__global__ __launch_bounds__(128) void ebar_partial(const float* __restrict__ E_tag,
                                                    float* __restrict__ partial)
{
    int blk = blockIdx.x;             // 512 blocks
    int tid = threadIdx.x;
    int v0 = blk * 196;
    int v1 = v0 + 196; if (v1 > NV) v1 = NV;
    if (tid < ND) {
        float acc = 0.f;
        for (int v = v0; v < v1; ++v) acc += E_tag[(size_t)v * ND + tid];
        partial[blk * ND + tid] = acc;
    }
}

__global__ __launch_bounds__(128) void ebar_final(const float* __restrict__ partial,
                                                  float* __restrict__ ebar)
{
    int tid = threadIdx.x;
    if (tid < ND) {
        float a = 0.f;
        for (int i = 0; i < 512; ++i) a += partial[i * ND + tid];
        ebar[tid] = a * (1.f / (float)NV);
    }
}

// ---------------------------------------------------------------------------
// prep_A: build A fragments for gates GEMM.
//   K layout: 48 kgrps of 8.  seg = kg>>4:  0 -> u = x[r]+eo*x[r+1]
//                                           1 -> v = x[r]+ei*x[r-1]
//                                           2 -> x
//   k_in = (kg&15)*8+j, valid k_in<100 else 0.
//   Afrag[kg][r][8] bf16.
// ---------------------------------------------------------------------------
__global__ __launch_bounds__(256) void prep_A(
    const int* __restrict__ seq, const int* __restrict__ lens,
    const float* __restrict__ E_ggnn, unsigned short* __restrict__ Afrag)
{
    __shared__ float xs[34][100];
    __shared__ float eo_s[34], ei_s[34];
    const int tid = threadIdx.x;
    const int r0  = blockIdx.x * 32;

    for (int idx = tid; idx < 34 * 25; idx += 256) {
        int row = idx / 25, qq = idx - row * 25;
        int rg = r0 - 1 + row;
        rg = rg < 0 ? 0 : (rg >= NBL ? NBL - 1 : rg);
        float4 e = *(const float4*)(E_ggnn + (size_t)seq[rg] * ND + 4 * qq);
        xs[row][4 * qq]     = e.x;
        xs[row][4 * qq + 1] = e.y;
        xs[row][4 * qq + 2] = e.z;
        xs[row][4 * qq + 3] = e.w;
    }
    for (int rr = tid; rr < 34; rr += 256) {
        int rg = r0 - 1 + rr;
        int rc = rg < 0 ? 0 : (rg >= NBL ? NBL - 1 : rg);
        int b = rc / NL, l = rc - b * NL;
        int lenb = lens[b];
        eo_s[rr] = (l < lenb - 1) ? 1.f : 0.f;
        ei_s[rr] = (l >= 1 && l <= lenb - 1) ? 1.f : 0.f;
    }
    __syncthreads();

    for (int idx = tid; idx < 32 * 48; idx += 256) {
        int rloc = idx / 48, kg = idx - rloc * 48;
        int seg = kg >> 4, kk = kg & 15;
        short8v o;
        float eo = eo_s[1 + rloc], ei = ei_s[1 + rloc];
#pragma unroll
        for (int j = 0; j < 8; ++j) {
            int k = kk * 8 + j;
            float v = 0.f;
            if (k < 100) {
                if (seg == 0)      v = xs[1 + rloc][k] + eo * xs[2 + rloc][k];
                else if (seg == 1) v = xs[1 + rloc][k] + ei * xs[rloc][k];
                else               v = xs[1 + rloc][k];
            }
            o[j] = (short)f2bf(v);
        }
        *(short8v*)(Afrag + ((size_t)kg * NBL + r0 + rloc) * 8) = o;
    }
}

// ---------------------------------------------------------------------------
// prep_B: Bfrag[kg][col 0..639][8] bf16.
//   seg0: col<300 -> W_ih[k][col];  seg1: col<300 -> W_ih[100+k][col];
//   seg2: 300<=col<600 -> W_hh[k][col-300];  else 0.
// ---------------------------------------------------------------------------
__global__ __launch_bounds__(256) void prep_B(
    const float* __restrict__ W_ih, const float* __restrict__ W_hh,
    unsigned short* __restrict__ Bfrag)
{
    int idx = blockIdx.x * 256 + threadIdx.x;   // (kg, col)
    if (idx >= 48 * 640) return;
    int kg = idx / 640, col = idx - kg * 640;
    int seg = kg >> 4, kk = kg & 15;
    short8v o;
#pragma unroll
    for (int j = 0; j < 8; ++j) {
        int k = kk * 8 + j;
        float v = 0.f;
        if (k < 100) {
            if (seg == 0 && col < 300)                 v = W_ih[k * 300 + col];
            else if (seg == 1 && col < 300)            v = W_ih[(100 + k) * 300 + col];
            else if (seg == 2 && col >= 300 && col < 600) v = W_hh[k * 300 + (col - 300)];
        }
        o[j] = (short)f2bf(v);
    }
    *(short8v*)(Bfrag + (size_t)idx * 8) = o;
}

// ---------------------------------------------------------------------------
// K1: gates GEMM via MFMA bf16 (single product).
//     M=25600 (128/block), N=640 (128/block, 600 valid), K=384 (48 kgrps).
//     A/B fragments read directly from global (L1/L2/L3 resident).
// ---------------------------------------------------------------------------
__global__ __launch_bounds__(256) void gates_mfma(
    const unsigned short* __restrict__ Afrag,
    const unsigned short* __restrict__ Bfrag,
    float* __restrict__ G)
{
    const int tid = threadIdx.x;
    const int r0  = blockIdx.x * 128;
    const int v0  = blockIdx.y * 128;
    const int lane = tid & 63;
    const int wv = tid >> 6;
    const int wm = wv >> 1, wn = wv & 1;
    const int q = lane >> 4, c = lane & 15;

    f32x4 acc[4][4];
#pragma unroll
    for (int fm = 0; fm < 4; ++fm)
#pragma unroll
        for (int fn = 0; fn < 4; ++fn) acc[fm][fn] = (f32x4)0.f;

    const bf16x8* Ap = (const bf16x8*)Afrag;
    const bf16x8* Bp = (const bf16x8*)Bfrag;

#pragma unroll
    for (int s = 0; s < 12; ++s) {
        const int kg = 4 * s + q;
        bf16x8 a[4], b[4];
#pragma unroll
        for (int fm = 0; fm < 4; ++fm)
            a[fm] = Ap[(size_t)kg * NBL + r0 + wm * 64 + fm * 16 + c];
#pragma unroll
        for (int fn = 0; fn < 4; ++fn)
            b[fn] = Bp[(size_t)kg * 640 + v0 + wn * 64 + fn * 16 + c];
#pragma unroll
        for (int fm = 0; fm < 4; ++fm)
#pragma unroll
            for (int fn = 0; fn < 4; ++fn)
                acc[fm][fn] = __builtin_amdgcn_mfma_f32_16x16x32_bf16(
                    a[fm], b[fn], acc[fm][fn], 0, 0, 0);
    }

#pragma unroll
    for (int fm = 0; fm < 4; ++fm) {
        int rb = r0 + wm * 64 + fm * 16 + q * 4;
#pragma unroll
        for (int fn = 0; fn < 4; ++fn) {
            int col = v0 + wn * 64 + fn * 16 + c;
            if (col < 600) {
#pragma unroll
                for (int r = 0; r < 4; ++r)
                    G[(size_t)(rb + r) * 600 + col] = acc[fm][fn][r];
            }
        }
    }
}

// ---------------------------------------------------------------------------
// K2: GRU elementwise
// ---------------------------------------------------------------------------
__global__ __launch_bounds__(256) void gru2(
    const int* __restrict__ seq, const float* __restrict__ E_ggnn,
    const float* __restrict__ G,
    const float* __restrict__ b_ih, const float* __restrict__ b_hh,
    float* __restrict__ h0)
{
    int idx = blockIdx.x * 256 + threadIdx.x;
    if (idx >= NBL * ND) return;
    int r = idx / ND, d = idx - r * ND;
    const float* Gr = G + (size_t)r * 600;
    float ir = Gr[d]       + b_ih[d];
    float iz = Gr[100 + d] + b_ih[100 + d];
    float ig = Gr[200 + d] + b_ih[200 + d];
    float hr = Gr[300 + d] + b_hh[d];
    float hz = Gr[400 + d] + b_hh[100 + d];
    float hg = Gr[500 + d] + b_hh[200 + d];
    float x  = E_ggnn[(size_t)seq[r] * ND + d];
    float rg = 1.f / (1.f + expf(-(ir + hr)));
    float zg = 1.f / (1.f + expf(-(iz + hz)));
    float ng = tanhf(ig + rg * hg);
    h0[idx] = (1.f - zg) * ng + zg * x;
}

// ---------------------------------------------------------------------------
// K45: per-batch fused tail.  Writes sess2 bf16 in MFMA fragment layout
//      A[kgrp 0..15][512 rows][8]  (k = kgrp*8+j, zero-padded k>=100).
// ---------------------------------------------------------------------------
__global__ __launch_bounds__(128) void fuse_kernel(
    const int* __restrict__ seq, const int* __restrict__ lens,
    const int* __restrict__ nei, const float* __restrict__ wei,
    const float* __restrict__ s_vec, const float* __restrict__ E_tag,
    const float* __restrict__ E_glob,
    const float* __restrict__ Wout_w, const float* __restrict__ Wout_b,
    const float* __restrict__ W_w,
    const float* __restrict__ W3_w, const float* __restrict__ W3_b,
    const float* __restrict__ W1_w, const float* __restrict__ W1_b,
    const float* __restrict__ q1_w,
    const float* __restrict__ W2_w, const float* __restrict__ W2_b,
    const float* __restrict__ G1_w, const float* __restrict__ G1_b,
    const float* __restrict__ G2_w, const float* __restrict__ G2_b,
    const float* __restrict__ ebar, const float* __restrict__ h0,
    unsigned short* __restrict__ A_hi)
{
    const int b = blockIdx.x, tid = threadIdx.x;
    __shared__ float t_emb[100], tw[100], twW[100], red[128];
    __shared__ float al[50], att[50];
    __shared__ float g0[100], cc[300], sess_s[100];
    __shared__ float sv[100], hnei[32][100], msg[100], xg[100], xg2[100];
    __shared__ float attg[32], score[32];
    __shared__ float scalars[4];      // 0: bd, 1: sm, 2: mean_b, 3: gate

    int lenb   = lens[b];
    int last_r = b * NL + (lenb - 1);
    int target = seq[last_r];

    if (tid < ND) {
        t_emb[tid] = E_tag[(size_t)target * ND + tid];
        sv[tid]    = s_vec[b * ND + tid];
    }
    __syncthreads();

    if (tid < ND) {
        float a = 0.f;
        for (int k = 0; k < ND; ++k) a += t_emb[k] * W_w[k * ND + tid];
        tw[tid] = a;
    }
    __syncthreads();

    if (tid < ND) {
        float a = 0.f;
        for (int d = 0; d < ND; ++d) a += Wout_w[tid * ND + d] * tw[d];
        twW[tid] = a;
    }
    red[tid] = (tid < ND) ? Wout_b[tid] * tw[tid] : 0.f;
    __syncthreads();
    for (int s = 64; s > 0; s >>= 1) { if (tid < s) red[tid] += red[tid + s]; __syncthreads(); }
    if (tid == 0) scalars[0] = red[0];
    __syncthreads();

    if (tid < NL) {
        const float* hr = h0 + (size_t)(b * NL + tid) * ND;
        float a = scalars[0];
        for (int k = 0; k < ND; ++k) a += hr[k] * twW[k];
        al[tid] = a;
    }
    __syncthreads();
    if (tid == 0) {
        float m = -1e30f;
        for (int l = 0; l < NL; ++l) m = fmaxf(m, al[l]);
        float s = 0.f;
        for (int l = 0; l < NL; ++l) { float e = expf(al[l] - m); att[l] = e; s += e; }
        float inv = 1.f / s, sm = 0.f;
        for (int l = 0; l < NL; ++l) { att[l] *= inv; if (l < lenb) sm += att[l]; }
        scalars[1] = sm;
    }
    __syncthreads();

    if (tid < ND) {
        float a = 0.f;
        for (int l = 0; l < lenb; ++l) a += att[l] * h0[(size_t)(b * NL + l) * ND + tid];
        g0[tid] = a;
    }
    __syncthreads();
    if (tid < ND) {
        float hg = 0.f, hl = 0.f;
        const float* hlast = h0 + (size_t)last_r * ND;
        for (int k = 0; k < ND; ++k) {
            float w = Wout_w[k * ND + tid];
            hg += g0[k] * w;
            hl += hlast[k] * w;
        }
        cc[tid]        = hg + scalars[1] * Wout_b[tid];
        cc[100 + tid]  = hl + Wout_b[tid];
        cc[200 + tid]  = t_emb[tid];
    }
    __syncthreads();

    if (tid < ND) {
        float a = W3_b[tid];
        for (int j = 0; j < 300; ++j) a += cc[j] * W3_w[j * ND + tid];
        sess_s[tid] = tanhf(a);
    }
    __syncthreads();
    red[tid] = (tid < ND) ? sess_s[tid] * ebar[tid] : 0.f;
    __syncthreads();
    for (int s = 64; s > 0; s >>= 1) { if (tid < s) red[tid] += red[tid + s]; __syncthreads(); }
    if (tid == 0) scalars[2] = red[0];
    __syncthreads();

    // ---- global encoder ----
    for (int idx = tid; idx < NKN * ND; idx += 128) {
        int k = idx / ND, d = idx - k * ND;
        hnei[k][d] = E_glob[(size_t)nei[b * NKN + k] * ND + d];
    }
    __syncthreads();

    {
        const int wv = tid >> 6, lane = tid & 63;
        for (int k2 = 0; k2 < NKN / 2; ++k2) {
            int k = k2 * 2 + wv;
            float p = 0.f;
            if (lane < 50) {
                float wk = wei[b * NKN + k];
                float a0 = W1_b[lane]      + wk * W1_w[100 * ND + lane];
                float a1 = W1_b[lane + 50] + wk * W1_w[100 * ND + lane + 50];
                for (int j = 0; j < ND; ++j) {
                    float t = hnei[k][j] * sv[j];
                    a0 += t * W1_w[j * ND + lane];
                    a1 += t * W1_w[j * ND + lane + 50];
                }
                p = tanhf(a0) * q1_w[lane] + tanhf(a1) * q1_w[lane + 50];
            }
            for (int off = 32; off > 0; off >>= 1) p += __shfl_down(p, off);
            if (lane == 0) score[k] = p;
        }
    }
    __syncthreads();

    if (tid == 0) {
        float m = -1e30f;
        for (int k = 0; k < NKN; ++k) m = fmaxf(m, score[k]);
        float s = 0.f;
        for (int k = 0; k < NKN; ++k) { float e = expf(score[k] - m); attg[k] = e; s += e; }
        float inv = 1.f / s;
        for (int k = 0; k < NKN; ++k) attg[k] *= inv;
    }
    __syncthreads();
    if (tid < ND) {
        float a = 0.f;
        for (int k = 0; k < NKN; ++k) a += attg[k] * hnei[k][tid];
        msg[tid] = a;
        xg[tid]  = E_glob[(size_t)target * ND + tid];
    }
    __syncthreads();
    if (tid < ND) {
        float a = W2_b[tid];
        for (int j = 0; j < ND; ++j) a += xg[j]  * W2_w[j * ND + tid];
        for (int j = 0; j < ND; ++j) a += msg[j] * W2_w[(100 + j) * ND + tid];
        xg2[tid] = fmaxf(a, 0.f);
    }
    __syncthreads();
    const float SCALE = (float)(1.0 - 49.0 / 50.0);
    if (tid < ND) {
        float a = W2_b[tid];
        for (int j = 0; j < ND; ++j) a += xg2[j] * W2_w[j * ND + tid];
        for (int j = 0; j < ND; ++j) a += msg[j] * W2_w[(100 + j) * ND + tid];
        xg[tid] = fmaxf(a, 0.f) * SCALE;
    }
    __syncthreads();

    if (tid < ND) {
        float a = G1_b[tid] + scalars[2] * G1_w[tid];
        for (int j = 0; j < ND; ++j) a += xg[j] * G1_w[(1 + j) * ND + tid];
        red[tid] = tanhf(a) * G2_w[tid];
    } else red[tid] = 0.f;
    __syncthreads();
    for (int s = 64; s > 0; s >>= 1) { if (tid < s) red[tid] += red[tid + s]; __syncthreads(); }
    if (tid == 0) scalars[3] = 1.f / (1.f + expf(-(red[0] + G2_b[0])));
    __syncthreads();

    // sess2 -> bf16 fragment layout (k = tid; tid>=100 pads zero)
    {
        float val = 0.f;
        if (tid < ND) {
            float g = scalars[3];
            val = g * xg[tid] + (1.f - g) * scalars[2];
        }
        int kgrp = tid >> 3, j = tid & 7;
        A_hi[kgrp * 4096 + b * 8 + j] = f2bf(val);
    }
}

// ---------------------------------------------------------------------------
// K6: out = sess2 @ E_tag^T via MFMA 16x16x32 bf16 (single product).
//     BM=128 x BN=128, 4 waves (64x64 each), Kp=128 (k>=100 zero).
// ---------------------------------------------------------------------------
__global__ __launch_bounds__(256) void out_gemm_mfma(
    const unsigned short* __restrict__ A_hi,
    const float* __restrict__ E_tag, float* __restrict__ out)
{
    __shared__ __align__(16) unsigned short Bs[16 * 1040];   // 1040 = 128*8 + 16 pad

    const int tid = threadIdx.x;
    const int v0  = blockIdx.x * 128;
    const int b0  = blockIdx.y * 128;

    // zero pad region (kgrp 12..15)
    {
        short8v z = {0, 0, 0, 0, 0, 0, 0, 0};
        for (int idx = tid; idx < 520; idx += 256)
            ((short8v*)(Bs + 12 * 1040))[idx] = z;
    }
    __syncthreads();

    for (int idx = tid; idx < 128 * 25; idx += 256) {
        int row = idx / 25, qq = idx - row * 25;
        int v = v0 + row;
        float4 e = make_float4(0.f, 0.f, 0.f, 0.f);
        if (v < NV) e = *(const float4*)(E_tag + (size_t)v * ND + 4 * qq);
        int kgrp = qq >> 1, jo = (qq & 1) * 4;
        float ev[4] = {e.x, e.y, e.z, e.w};
        short4v h;
#pragma unroll
        for (int t = 0; t < 4; ++t) h[t] = (short)f2bf(ev[t]);
        *(short4v*)(Bs + kgrp * 1040 + row * 8 + jo) = h;
    }
    __syncthreads();

    const int lane = tid & 63;
    const int wv = tid >> 6;
    const int wm = wv >> 1, wn = wv & 1;
    const int q = lane >> 4, c = lane & 15;

    f32x4 acc[4][4];
#pragma unroll
    for (int fm = 0; fm < 4; ++fm)
#pragma unroll
        for (int fn = 0; fn < 4; ++fn) acc[fm][fn] = (f32x4)0.f;

    const bf16x8* Ah = (const bf16x8*)A_hi;

#pragma unroll
    for (int s = 0; s < 4; ++s) {
        const int kg = 4 * s + q;
        bf16x8 a[4], b[4];
#pragma unroll
        for (int fm = 0; fm < 4; ++fm) {
            int row = b0 + wm * 64 + fm * 16 + c;
            a[fm] = Ah[kg * 512 + row];
        }
#pragma unroll
        for (int fn = 0; fn < 4; ++fn) {
            int vloc = wn * 64 + fn * 16 + c;
            b[fn] = *(const bf16x8*)(Bs + kg * 1040 + vloc * 8);
        }
#pragma unroll
        for (int fm = 0; fm < 4; ++fm)
#pragma unroll
            for (int fn = 0; fn < 4; ++fn)
                acc[fm][fn] = __builtin_amdgcn_mfma_f32_16x16x32_bf16(
                    a[fm], b[fn], acc[fm][fn], 0, 0, 0);
    }

#pragma unroll
    for (int fm = 0; fm < 4; ++fm) {
        int row_base = b0 + wm * 64 + fm * 16 + q * 4;
#pragma unroll
        for (int fn = 0; fn < 4; ++fn) {
            int col = v0 + wn * 64 + fn * 16 + c;
            if (col < NV) {
#pragma unroll
                for (int r = 0; r < 4; ++r)
                    out[(size_t)(row_base + r) * NV + col] = acc[fm][fn][r];
            }
        }
    }
}

// ---------------------------------------------------------------------------
extern "C" void kernel_launch(void* const* d_in, const int* in_sizes, int n_in,
                              void* d_out, int out_size, void* d_ws, size_t ws_size,
                              hipStream_t stream)
{
    const int*   seq    = (const int*)  d_in[0];
    const int*   lens   = (const int*)  d_in[1];
    const int*   nei    = (const int*)  d_in[2];
    const float* wei    = (const float*)d_in[3];
    const float* s_vec  = (const float*)d_in[4];
    const float* E_tag  = (const float*)d_in[5];
    const float* E_ggnn = (const float*)d_in[6];
    const float* E_glob = (const float*)d_in[7];
    const float* W_ih   = (const float*)d_in[8];
    const float* b_ih   = (const float*)d_in[9];
    const float* W_hh   = (const float*)d_in[10];
    const float* b_hh   = (const float*)d_in[11];
    const float* Wout_w = (const float*)d_in[12];
    const float* Wout_b = (const float*)d_in[13];
    const float* W_w    = (const float*)d_in[14];
    const float* W3_w   = (const float*)d_in[15];
    const float* W3_b   = (const float*)d_in[16];
    const float* W1_w   = (const float*)d_in[17];
    const float* W1_b   = (const float*)d_in[18];
    const float* q1_w   = (const float*)d_in[19];
    const float* W2_w   = (const float*)d_in[20];
    const float* W2_b   = (const float*)d_in[21];
    const float* G1_w   = (const float*)d_in[22];
    const float* G1_b   = (const float*)d_in[23];
    const float* G2_w   = (const float*)d_in[24];
    const float* G2_b   = (const float*)d_in[25];

    float* out = (float*)d_out;
    // d_out staging (51.2M floats total; all consumed before out_gemm writes):
    //   G     floats [0 .. 15.36M)
    //   Afrag ushorts at float-offset 16M (48*25600*8 = 9.83M ushorts)
    //   Bfrag ushorts at float-offset 21M (48*640*8 = 245.8K ushorts)
    float* Gm = out;
    unsigned short* Afrag = (unsigned short*)(out + 16000000);
    unsigned short* Bfrag = (unsigned short*)(out + 21000000);

    float* ws      = (float*)d_ws;
    float* h0      = ws;                            // 2.56M floats
    float* partial = ws + 2560000;                  // 51.2K
    float* ebar    = ws + 2611200;                  // 128
    unsigned short* A_hi = (unsigned short*)(ws + 2611328);  // 65536 bf16

    ebar_partial<<<512, 128, 0, stream>>>(E_tag, partial);
    ebar_final<<<1, 128, 0, stream>>>(partial, ebar);
    prep_A<<<NBL / 32, 256, 0, stream>>>(seq, lens, E_ggnn, Afrag);
    prep_B<<<(48 * 640 + 255) / 256, 256, 0, stream>>>(W_ih, W_hh, Bfrag);
    gates_mfma<<<dim3(NBL / 128, 5), 256, 0, stream>>>(Afrag, Bfrag, Gm);
    gru2<<<(NBL * ND + 255) / 256, 256, 0, stream>>>(seq, E_ggnn, Gm, b_ih, b_hh, h0);
    fuse_kernel<<<NB, 128, 0, stream>>>(seq, lens, nei, wei, s_vec, E_tag, E_glob,
                                        Wout_w, Wout_b, W_w, W3_w, W3_b,
                                        W1_w, W1_b, q1_w, W2_w, W2_b,
                                        G1_w, G1_b, G2_w, G2_b, ebar, h0, A_hi);
    out_gemm_mfma<<<dim3((NV + 127) / 128, NB / 128), 256, 0, stream>>>(A_hi, E_tag, out);
}